// Round 2
// baseline (315.696 us; speedup 1.0000x reference)
//
#include <hip/hip_runtime.h>
#include <hip/hip_bf16.h>
#include <stdint.h>

typedef __bf16 bf16;
typedef __bf16 v8bf __attribute__((ext_vector_type(8)));
typedef float  v4f  __attribute__((ext_vector_type(4)));

#define TSEQ   2048
#define HIDDIM 2048
#define NHEAD  16
#define HDIM   128

// async global->LDS, 16B per lane, LDS dest = wave-uniform base + lane*16 (m97 pattern)
__device__ __forceinline__ void async16(void* lds, const void* g)
{
    __builtin_amdgcn_global_load_lds(
        (__attribute__((address_space(1))) void*)(uintptr_t)g,
        (__attribute__((address_space(3))) void*)(unsigned int)(uintptr_t)lds,
        16, 0, 0);
}

// ---------------- f32 -> bf16 bulk convert: 5 matrices of TSEQ*HIDDIM ----------------
__global__ __launch_bounds__(256) void conv5(const float* __restrict__ s0, bf16* __restrict__ d0,
                                             const float* __restrict__ s1, bf16* __restrict__ d1,
                                             const float* __restrict__ s2, bf16* __restrict__ d2,
                                             const float* __restrict__ s3, bf16* __restrict__ d3,
                                             const float* __restrict__ s4, bf16* __restrict__ d4)
{
    const float* src; bf16* dst;
    switch (blockIdx.y) {
        case 0: src = s0; dst = d0; break;
        case 1: src = s1; dst = d1; break;
        case 2: src = s2; dst = d2; break;
        case 3: src = s3; dst = d3; break;
        default: src = s4; dst = d4; break;
    }
    const size_t i = ((size_t)blockIdx.x * 256 + threadIdx.x) * 8;
    const float4 a = *(const float4*)(src + i);
    const float4 b = *(const float4*)(src + i + 4);
    v8bf o;
    o[0] = (bf16)a.x; o[1] = (bf16)a.y; o[2] = (bf16)a.z; o[3] = (bf16)a.w;
    o[4] = (bf16)b.x; o[5] = (bf16)b.y; o[6] = (bf16)b.z; o[7] = (bf16)b.w;
    *(v8bf*)(dst + i) = o;
}

// ---------------- NT GEMM: C[M,N] = A[M,K] * B[N,K]^T, 128x128 tile, BK=32 ----------------
template <typename CT>
__device__ __forceinline__ void gemm_body(const bf16* __restrict__ A,
                                          const bf16* __restrict__ B,
                                          CT* __restrict__ C,
                                          int m0, int n0, int K, int ldc)
{
    __shared__ __attribute__((aligned(16))) bf16 sA[128*32];
    __shared__ __attribute__((aligned(16))) bf16 sB[128*32];
    const int tid  = threadIdx.x;
    const int lane = tid & 63;
    const int w    = tid >> 6;           // wave 0..3
    const int wm   = w >> 1, wn = w & 1; // 2x2 waves of 64x64
    const int quad = lane >> 4, lr = lane & 15;
    const int srow = lane >> 2;          // staging: 16 rows x 4 lanes/row
    const int scol = (lane & 3) * 8;

    const bf16* gA0 = A + (size_t)(m0 + w*32 + srow) * K + scol;
    const bf16* gB0 = B + (size_t)(n0 + w*32 + srow) * K + scol;
    bf16* lA0 = &sA[w*1024];
    bf16* lB0 = &sB[w*1024];

    v4f acc[4][4] = {};

    for (int kt = 0; kt < K; kt += 32) {
        __syncthreads();                         // prev-iter LDS reads done
        async16(lA0,       gA0 + kt);
        async16(lA0 + 512, gA0 + (size_t)16*K + kt);
        async16(lB0,       gB0 + kt);
        async16(lB0 + 512, gB0 + (size_t)16*K + kt);
        __syncthreads();                         // drains vmcnt -> tiles visible
        v8bf a[4], b[4];
#pragma unroll
        for (int i = 0; i < 4; ++i)
            a[i] = *(const v8bf*)&sA[(wm*64 + i*16 + lr)*32 + quad*8];
#pragma unroll
        for (int j = 0; j < 4; ++j)
            b[j] = *(const v8bf*)&sB[(wn*64 + j*16 + lr)*32 + quad*8];
#pragma unroll
        for (int i = 0; i < 4; ++i)
#pragma unroll
            for (int j = 0; j < 4; ++j)
                acc[i][j] = __builtin_amdgcn_mfma_f32_16x16x32_bf16(a[i], b[j], acc[i][j], 0, 0, 0);
    }

#pragma unroll
    for (int i = 0; i < 4; ++i) {
        const int row_b = m0 + wm*64 + i*16 + quad*4;
#pragma unroll
        for (int j = 0; j < 4; ++j) {
            const int col = n0 + wn*64 + j*16 + lr;
#pragma unroll
            for (int r = 0; r < 4; ++r)
                C[(size_t)(row_b + r)*ldc + col] = (CT)acc[i][j][r];
        }
    }
}

__global__ __launch_bounds__(256) void gemm_qkv(const bf16* __restrict__ A,
    const bf16* __restrict__ Wq, const bf16* __restrict__ Wk, const bf16* __restrict__ Wv,
    bf16* __restrict__ qb, bf16* __restrict__ kb, bf16* __restrict__ vb)
{
    const int which = blockIdx.x >> 4;                   // 0:q 1:k 2:v
    const int n0 = (blockIdx.x & 15) * 128;
    const int m0 = blockIdx.y * 128;
    const bf16* B = (which == 0) ? Wq : (which == 1) ? Wk : Wv;
    bf16* C = (which == 0) ? qb : (which == 1) ? kb : vb;
    gemm_body<bf16>(A, B, C, m0, n0, HIDDIM, HIDDIM);
}

__global__ __launch_bounds__(256) void gemm_out(const bf16* __restrict__ A,
    const bf16* __restrict__ B, float* __restrict__ C)
{
    gemm_body<float>(A, B, C, blockIdx.y*128, blockIdx.x*128, HIDDIM, HIDDIM);
}

// ---------------- ReBased feature map: y = LN(x*gamma+beta), q also * D^-0.5 ----------------
__global__ __launch_bounds__(256) void fmap(bf16* __restrict__ qb, bf16* __restrict__ kb,
                                            const float* __restrict__ gamma,
                                            const float* __restrict__ beta)
{
    const int rid  = blockIdx.x * 4 + (threadIdx.x >> 6);   // 0 .. 2*T*H-1
    const int lane = threadIdx.x & 63;
    bf16* base = (rid < TSEQ*NHEAD) ? (qb + (size_t)rid * HDIM)
                                    : (kb + (size_t)(rid - TSEQ*NHEAD) * HDIM);
    const float scale = (rid < TSEQ*NHEAD) ? 0.08838834764831845f : 1.0f; // D^-0.5 on q only

    const bf16 x0b = base[lane*2], x1b = base[lane*2+1];
    const float g0 = gamma[lane*2], g1 = gamma[lane*2+1];
    const float b0 = beta[lane*2],  b1 = beta[lane*2+1];
    float x0 = (float)x0b*g0 + b0;
    float x1 = (float)x1b*g1 + b1;
    float s  = x0 + x1;
    float sq = x0*x0 + x1*x1;
#pragma unroll
    for (int off = 1; off < 64; off <<= 1) { s += __shfl_xor(s, off); sq += __shfl_xor(sq, off); }
    const float mu   = s * (1.0f/128.0f);
    float var        = sq * (1.0f/128.0f) - mu*mu;
    var = fmaxf(var, 0.0f);
    const float rstd = rsqrtf(var + 1e-5f);
    base[lane*2]   = (bf16)((x0 - mu) * rstd * scale);
    base[lane*2+1] = (bf16)((x1 - mu) * rstd * scale);
}

// ---------------- 2048x2048 transpose (vt[c][t] = vb[t][c]) ----------------
__global__ __launch_bounds__(256) void transpose2048(const bf16* __restrict__ src,
                                                     bf16* __restrict__ dst)
{
    __shared__ __attribute__((aligned(16))) bf16 tile[64][72];
    const int t0 = blockIdx.y * 64, c0 = blockIdx.x * 64;
    const int tid = threadIdx.x;
    const int r = tid >> 3;            // 0..31
    const int c = (tid & 7) * 8;       // 0..56
#pragma unroll
    for (int p = 0; p < 2; ++p) {
        const int rr = r + p*32;
        *(v8bf*)&tile[rr][c] = *(const v8bf*)(src + (size_t)(t0+rr)*HIDDIM + c0 + c);
    }
    __syncthreads();
#pragma unroll
    for (int p = 0; p < 2; ++p) {
        const int orow = r + p*32;     // output row = original column
        v8bf o;
#pragma unroll
        for (int i = 0; i < 8; ++i) o[i] = tile[c + i][orow];
        *(v8bf*)(dst + (size_t)(c0+orow)*HIDDIM + t0 + c) = o;
    }
}

// ---------------- quadratic causal attention ----------------
// grid (16 qt-tiles, 16 heads); block 256 = 4 waves, wave w owns q rows [32w,32w+32).
// Per 64-key chunk: S = (Q K^T)^2 masked (z += rowsum of rounded S), S->LDS(bf16), O += S*V.
__global__ __launch_bounds__(256, 2) void attn(const bf16* __restrict__ qb,
                                               const bf16* __restrict__ kb,
                                               const bf16* __restrict__ vt,
                                               bf16* __restrict__ ob)
{
    __shared__ __attribute__((aligned(16))) bf16 sK[64*136];   // [s][d], pad 8
    __shared__ __attribute__((aligned(16))) bf16 sV[128*72];   // [d][s], pad 8
    __shared__ __attribute__((aligned(16))) bf16 sS[128*72];   // [q][s], pad 8
    const int h   = blockIdx.y;
    const int qt  = 15 - blockIdx.x;          // big workloads scheduled first
    const int tid = threadIdx.x, lane = tid & 63, w = tid >> 6;
    const int quad = lane >> 4, lr = lane & 15;

    // Q fragments (A-layout), held in registers for the whole block
    v8bf qa[2][4];
    {
        const bf16* q0 = qb + (size_t)(qt*128 + w*32 + lr)*HIDDIM + h*HDIM + quad*8;
#pragma unroll
        for (int mi = 0; mi < 2; ++mi)
#pragma unroll
            for (int ks = 0; ks < 4; ++ks)
                qa[mi][ks] = *(const v8bf*)(q0 + (size_t)mi*16*HIDDIM + ks*32);
    }

    v4f  o[2][8] = {};
    float z[2][4] = {};
    const int nchunks = 2*qt + 2;

    for (int ch = 0; ch < nchunks; ++ch) {
        const int s0 = ch * 64;
        const bool diag = (s0 + 63 > qt*128);
        __syncthreads();                        // prev-chunk LDS reads done
        {   // stage K tile [64 s][128 d]
            const int r  = tid >> 4;            // 0..15
            const int c  = (tid & 15) * 8;
#pragma unroll
            for (int p = 0; p < 4; ++p) {
                const int rr = r + p*16;
                *(v8bf*)&sK[rr*136 + c] =
                    *(const v8bf*)(kb + (size_t)(s0+rr)*HIDDIM + h*HDIM + c);
            }
            // stage Vt tile [128 d][64 s]
            const int r2 = tid >> 3;            // 0..31
            const int c2 = (tid & 7) * 8;
#pragma unroll
            for (int p = 0; p < 4; ++p) {
                const int rr = r2 + p*32;
                *(v8bf*)&sV[rr*72 + c2] =
                    *(const v8bf*)(vt + (size_t)(h*HDIM+rr)*HIDDIM + s0 + c2);
            }
        }
        __syncthreads();                        // tiles visible

        // QK^T -> square/mask -> z, sS (sS rows are wave-private: no barrier needed)
        v8bf kbf[4][4];
#pragma unroll
        for (int nj = 0; nj < 4; ++nj)
#pragma unroll
            for (int ks = 0; ks < 4; ++ks)
                kbf[nj][ks] = *(const v8bf*)&sK[(nj*16 + lr)*136 + ks*32 + quad*8];
#pragma unroll
        for (int mi = 0; mi < 2; ++mi) {
#pragma unroll
            for (int nj = 0; nj < 4; ++nj) {
                v4f s4 = {0.f, 0.f, 0.f, 0.f};
#pragma unroll
                for (int ks = 0; ks < 4; ++ks)
                    s4 = __builtin_amdgcn_mfma_f32_16x16x32_bf16(qa[mi][ks], kbf[nj][ks], s4, 0, 0, 0);
                const int row_l = w*32 + mi*16 + quad*4;
                const int col   = nj*16 + lr;
                const int qg    = qt*128 + row_l;
                const int sg    = s0 + col;
#pragma unroll
                for (int r = 0; r < 4; ++r) {
                    float val = s4[r] * s4[r];
                    if (diag && (sg > qg + r)) val = 0.0f;
                    const bf16 vb16 = (bf16)val;
                    z[mi][r] += (float)vb16;    // consistent with what multiplies V
                    sS[(row_l + r)*72 + col] = vb16;
                }
            }
        }

        // O += S * V
#pragma unroll
        for (int ks = 0; ks < 2; ++ks) {
            v8bf sa[2];
#pragma unroll
            for (int mi = 0; mi < 2; ++mi)
                sa[mi] = *(const v8bf*)&sS[(w*32 + mi*16 + lr)*72 + ks*32 + quad*8];
#pragma unroll
            for (int nd = 0; nd < 8; ++nd) {
                const v8bf vb = *(const v8bf*)&sV[(nd*16 + lr)*72 + ks*32 + quad*8];
#pragma unroll
                for (int mi = 0; mi < 2; ++mi)
                    o[mi][nd] = __builtin_amdgcn_mfma_f32_16x16x32_bf16(sa[mi], vb, o[mi][nd], 0, 0, 0);
            }
        }
    }

    // z: sum across the 16-lane group (each lane accumulated 4 of every 64 cols)
#pragma unroll
    for (int mi = 0; mi < 2; ++mi)
#pragma unroll
        for (int r = 0; r < 4; ++r) {
            float zz = z[mi][r];
            zz += __shfl_xor(zz, 1); zz += __shfl_xor(zz, 2);
            zz += __shfl_xor(zz, 4); zz += __shfl_xor(zz, 8);
            z[mi][r] = zz + 1e-5f;
        }

    // epilogue: ob[t][h*128+d] = O / (z + eps)
#pragma unroll
    for (int mi = 0; mi < 2; ++mi) {
        const int row_l = w*32 + mi*16 + quad*4;
        const size_t rbase = (size_t)(qt*128 + row_l)*HIDDIM + h*HDIM;
#pragma unroll
        for (int nd = 0; nd < 8; ++nd) {
            const int col = nd*16 + lr;
#pragma unroll
            for (int r = 0; r < 4; ++r)
                ob[rbase + (size_t)r*HIDDIM + col] = (bf16)(o[mi][nd][r] / z[mi][r]);
        }
    }
}

extern "C" void kernel_launch(void* const* d_in, const int* in_sizes, int n_in,
                              void* d_out, int out_size, void* d_ws, size_t ws_size,
                              hipStream_t stream)
{
    const float* hs    = (const float*)d_in[0];
    const float* Wq    = (const float*)d_in[1];
    const float* Wk    = (const float*)d_in[2];
    const float* Wv    = (const float*)d_in[3];
    const float* Wo    = (const float*)d_in[4];
    const float* gamma = (const float*)d_in[5];
    const float* beta  = (const float*)d_in[6];
    float* outp = (float*)d_out;

    const size_t MAT = (size_t)TSEQ * HIDDIM;     // 4.19M elems

    // bf16 workspace slots (8.39 MB each). Wq_b/Wk_b live inside d_out (exactly
    // 2 slots = 16.78 MB), dead before gemm_out writes it. vt aliases hs_b.
    bf16* ws  = (bf16*)d_ws;
    bf16* hs_b = ws + 0*MAT;
    bf16* vt   = hs_b;                            // alias: hs_b dead after gemm_qkv
    bf16* Wv_b = ws + 1*MAT;
    bf16* Wo_b = ws + 2*MAT;
    bf16* qb   = ws + 3*MAT;
    bf16* kb   = ws + 4*MAT;
    bf16* vb   = ws + 5*MAT;
    bf16* ob   = vb;                              // alias: vb dead after transpose
    bf16* Wq_b = (bf16*)d_out;
    bf16* Wk_b = (bf16*)d_out + MAT;

    conv5<<<dim3(2048, 5), 256, 0, stream>>>(hs, hs_b, Wq, Wq_b, Wk, Wk_b, Wv, Wv_b, Wo, Wo_b);
    gemm_qkv<<<dim3(48, 16), 256, 0, stream>>>(hs_b, Wq_b, Wk_b, Wv_b, qb, kb, vb);
    fmap<<<dim3(2*TSEQ*NHEAD/4), 256, 0, stream>>>(qb, kb, gamma, beta);
    transpose2048<<<dim3(32, 32), 256, 0, stream>>>(vb, vt);
    attn<<<dim3(16, 16), 256, 0, stream>>>(qb, kb, vt, ob);
    gemm_out<<<dim3(16, 16), 256, 0, stream>>>(ob, Wo_b, outp);
}